// Round 1
// baseline (371.649 us; speedup 1.0000x reference)
//
#include <hip/hip_runtime.h>
#include <stdint.h>

// ---------------------------------------------------------------------------
// DistributedAttention on MI355X (gfx950)
//   q = x Wq^T + bq ; k = x Wk^T + bk ; v = x Wv^T + bv
//   P = softmax(q k^T / 8) ; out = P v Wo^T + bo
// Factorization (R7, kept):
//   F    = Wo . Wv                  (2.1 GF, replaces the 17.2 GF v-proj)
//   Vot  = F . x^T   per batch      ([H][S] bf16)
//   P_un = exp(q k^T / 8)           (bf16 + atomic fp32 rowsums)
//   out  = (P_un . Vot^T)/rowsum + bfinal,  bfinal = bo + Wo.bv
// R9: port the two dominant GEMMs (scores, final) to a 256-wide phase-split
//     schedule (learn_hip m196-m201 ladder): 8 waves, BK=64, double-buffered
//     xor-swizzled LDS, global_load_lds(16B), raw s_barrier (no implicit
//     vmcnt drains), counted s_waitcnt vmcnt(N) once per K-tile (never 0 in
//     steady state), region-granular prefetch 2-3 phases ahead, setprio(1)
//     around each 16-MFMA cluster, sched_barrier(0) phase fences.
//     scores: 256x256 tiles (512 blocks); final: 128x256 (256 blocks = 1/CU).
//     cvt/QKF/Vot keep the proven 128^2 path. Accumulation order per element
//     is unchanged -> numerics bit-identical to R8.
// ---------------------------------------------------------------------------

typedef __bf16 bf16x8 __attribute__((ext_vector_type(8)));
typedef float  f32x4  __attribute__((ext_vector_type(4)));

__device__ __forceinline__ unsigned short f32_to_bf16_rne(float f) {
    uint32_t u = __builtin_bit_cast(uint32_t, f);
    uint32_t r = (u + 0x7FFFu + ((u >> 16) & 1u)) >> 16;
    return (unsigned short)r;
}

#define BM 128
#define BN 128
#define BK 64

// ---------------------------------------------------------------------------
// One-dispatch prep, 11544 blocks (unchanged from R8).
// ---------------------------------------------------------------------------
__global__ __launch_bounds__(256) void cvt_all(
    const float* __restrict__ x,
    const float* __restrict__ Wq, const float* __restrict__ Wk,
    const float* __restrict__ Wo, const float* __restrict__ Wv,
    const float* __restrict__ bv, const float* __restrict__ bo,
    unsigned short* __restrict__ x16, unsigned short* __restrict__ w16,
    float* __restrict__ rsum, float* __restrict__ bfinal)
{
    const int b = blockIdx.x, tid = threadIdx.x;
    if (b < 8192) {
        int i = (b * 256 + tid) * 4;
        float4 v = *(const float4*)(x + i);
        ushort4 o;
        o.x = f32_to_bf16_rne(v.x); o.y = f32_to_bf16_rne(v.y);
        o.z = f32_to_bf16_rne(v.z); o.w = f32_to_bf16_rne(v.w);
        *(ushort4*)(x16 + i) = o;
    } else if (b < 11264) {
        int bb = b - 8192;
        int which = bb >> 10;
        const float* src = which == 0 ? Wq : which == 1 ? Wk : Wo;
        int i = ((bb & 1023) * 256 + tid) * 4;
        float4 v = *(const float4*)(src + i);
        ushort4 o;
        o.x = f32_to_bf16_rne(v.x); o.y = f32_to_bf16_rne(v.y);
        o.z = f32_to_bf16_rne(v.z); o.w = f32_to_bf16_rne(v.w);
        *(ushort4*)(w16 + (size_t)which * 1048576 + i) = o;
    } else if (b < 11520) {
        __shared__ unsigned short tl[64 * 68];   // [c][r], stride 68
        int t = b - 11264, tr = t >> 4, tc = t & 15;
        #pragma unroll
        for (int it = 0; it < 4; ++it) {
            int r  = it * 16 + (tid >> 4);
            int c0 = (tid & 15) * 4;
            float4 v = *(const float4*)(Wv + (size_t)(tr * 64 + r) * 1024 + tc * 64 + c0);
            tl[(c0 + 0) * 68 + r] = f32_to_bf16_rne(v.x);
            tl[(c0 + 1) * 68 + r] = f32_to_bf16_rne(v.y);
            tl[(c0 + 2) * 68 + r] = f32_to_bf16_rne(v.z);
            tl[(c0 + 3) * 68 + r] = f32_to_bf16_rne(v.w);
        }
        __syncthreads();
        #pragma unroll
        for (int it = 0; it < 4; ++it) {
            int c  = it * 16 + (tid >> 4);
            int r0 = (tid & 15) * 4;
            ushort4 o;
            o.x = tl[c * 68 + r0 + 0]; o.y = tl[c * 68 + r0 + 1];
            o.z = tl[c * 68 + r0 + 2]; o.w = tl[c * 68 + r0 + 3];
            *(ushort4*)(w16 + (size_t)3 * 1048576 + (size_t)(tc * 64 + c) * 1024 + tr * 64 + r0) = o;
        }
    } else if (b < 11536) {
        int bb = b - 11520;
        int lane = tid & 63, wv_ = tid >> 6;
        int rowBase = bb * 64 + wv_ * 16;
        for (int rr = 0; rr < 16; ++rr) {
            int row = rowBase + rr;
            float partial = 0.f;
            #pragma unroll
            for (int t2 = 0; t2 < 16; ++t2) {
                int h = t2 * 64 + lane;
                partial += Wo[(size_t)row * 1024 + h] * bv[h];
            }
            #pragma unroll
            for (int off = 32; off > 0; off >>= 1)
                partial += __shfl_xor(partial, off, 64);
            if (lane == 0) bfinal[row] = bo[row] + partial;
        }
    } else {
        int i = ((b - 11536) * 256 + tid) * 4;
        *(float4*)(rsum + i) = float4{0.f, 0.f, 0.f, 0.f};
    }
}

// ---------------------------------------------------------------------------
// Proven 128^2 K-loop (R5 codegen) — still used by QKF and Vot.
// ---------------------------------------------------------------------------
__device__ __forceinline__ void gemm_core(
    const unsigned short* __restrict__ Ab,
    const unsigned short* __restrict__ Bb,
    unsigned short* ldsA, unsigned short* ldsB,
    int mBase, int nBase, int lane, int wave, int K, f32x4 (&acc)[4][4])
{
    const int quad = lane >> 4;
    const int l16  = lane & 15;
    const int wr   = wave >> 1;
    const int wc   = wave & 1;

    for (int k0 = 0; k0 < K; k0 += BK) {
        #pragma unroll
        for (int i = 0; i < 4; ++i) {
            int base = (i * 4 + wave) * 64;
            int s    = base + lane;
            int row  = s >> 3;
            int col  = ((s ^ (s >> 3)) & 7) * 8;
            __builtin_amdgcn_global_load_lds(
                (const __attribute__((address_space(1))) void*)(Ab + (size_t)(mBase + row) * K + (size_t)(k0 + col)),
                (__attribute__((address_space(3))) void*)(&ldsA[base * 8]),
                16, 0, 0);
        }
        #pragma unroll
        for (int i = 0; i < 4; ++i) {
            int base = (i * 4 + wave) * 64;
            int s    = base + lane;
            int row  = s >> 3;
            int col  = ((s ^ (s >> 3)) & 7) * 8;
            __builtin_amdgcn_global_load_lds(
                (const __attribute__((address_space(1))) void*)(Bb + (size_t)(nBase + row) * K + (size_t)(k0 + col)),
                (__attribute__((address_space(3))) void*)(&ldsB[base * 8]),
                16, 0, 0);
        }
        __syncthreads();

        #pragma unroll
        for (int kk = 0; kk < 2; ++kk) {
            bf16x8 af[4], bfv[4];
            #pragma unroll
            for (int mi = 0; mi < 4; ++mi) {
                int r = wr * 64 + mi * 16 + l16;
                int c = kk * 4 + quad;
                af[mi] = *(const bf16x8*)(&ldsA[r * BK + (((c ^ r) & 7) << 3)]);
            }
            #pragma unroll
            for (int ni = 0; ni < 4; ++ni) {
                int r = wc * 64 + ni * 16 + l16;
                int c = kk * 4 + quad;
                bfv[ni] = *(const bf16x8*)(&ldsB[r * BK + (((c ^ r) & 7) << 3)]);
            }
            #pragma unroll
            for (int mi = 0; mi < 4; ++mi)
                #pragma unroll
                for (int ni = 0; ni < 4; ++ni)
                    acc[mi][ni] = __builtin_amdgcn_mfma_f32_16x16x32_bf16(
                        af[mi], bfv[ni], acc[mi][ni], 0, 0, 0);
        }
        __syncthreads();
    }
}

// ---------------------------------------------------------------------------
// Generic z-batched A.Bt^T GEMM on the 128^2 path (MODE 1 only now: Vot).
// ---------------------------------------------------------------------------
template <int MODE>
__global__ __launch_bounds__(256) void gemm_bt(
    const unsigned short* __restrict__ A,
    const unsigned short* __restrict__ Bt,
    void* __restrict__ C,
    const float* __restrict__ b0, float* __restrict__ rowsum,
    float alpha, int M, int N, int K,
    long long aZ, long long bZ, long long cZ)
{
    __shared__ unsigned short ldsA[BM * BK];
    __shared__ unsigned short ldsB[BN * BK];

    const int NB = gridDim.x, MBt = gridDim.y;
    int l  = blockIdx.x + gridDim.x * (blockIdx.y + gridDim.y * blockIdx.z);
    int xcd = l & 7;
    int t   = l >> 3;
    int MBX = MBt >> 1;
    int NBX = NB >> 2;
    int mbl = t % MBX;
    int r1  = t / MBX;
    int nbi = r1 % NBX;
    int zb  = r1 / NBX;
    int mb  = (xcd >> 2) * MBX + mbl;
    int nb  = (xcd & 3) * NBX + nbi;

    const unsigned short* Ab = A  + (size_t)zb * aZ;
    const unsigned short* Bb = Bt + (size_t)zb * bZ;

    const int tid  = threadIdx.x;
    const int lane = tid & 63;
    const int wave = tid >> 6;
    const int quad = lane >> 4;
    const int l16  = lane & 15;
    const int wr   = wave >> 1;
    const int wc   = wave & 1;
    const int mBase = mb * BM;
    const int nBase = nb * BN;

    f32x4 acc[4][4] = {};
    gemm_core(Ab, Bb, ldsA, ldsB, mBase, nBase, lane, wave, K, acc);

    if (MODE == 1) {
        unsigned short* Cz = (unsigned short*)C + (size_t)zb * cZ;
        #pragma unroll
        for (int mi = 0; mi < 4; ++mi)
            #pragma unroll
            for (int ni = 0; ni < 4; ++ni) {
                int col = nBase + wc * 64 + ni * 16 + l16;
                float b = b0 ? b0[col] : 0.f;
                #pragma unroll
                for (int r = 0; r < 4; ++r) {
                    int row = mBase + wr * 64 + mi * 16 + quad * 4 + r;
                    Cz[(size_t)row * N + col] = f32_to_bf16_rne(acc[mi][ni][r] + b);
                }
            }
    }
}

// ---------------------------------------------------------------------------
// Q/K projections + F = Wo.Wv in one dispatch (unchanged from R8).
// ---------------------------------------------------------------------------
__global__ __launch_bounds__(256) void gemm_qkf(
    const unsigned short* __restrict__ x16,
    const unsigned short* __restrict__ w16,   // [Wq|Wk|Wo|WvT] x 1048576 elems
    unsigned short* __restrict__ q16,
    unsigned short* __restrict__ k16,
    unsigned short* __restrict__ F16,
    const float* __restrict__ bq, const float* __restrict__ bk)
{
    __shared__ unsigned short ldsA[BM * BK];
    __shared__ unsigned short ldsB[BN * BK];

    int l   = blockIdx.x;                 // 1088 = 8 * 136
    int idx = (l & 7) * 136 + (l >> 3);   // XCD-contiguous

    const unsigned short *Ab, *Bb;
    unsigned short* Cb;
    const float* bias;
    int mBase, nBase;
    if (idx < 1024) {
        int role = idx >> 9;              // 0:q 1:k
        int s    = idx & 511;
        mBase = (s >> 3) * BM; nBase = (s & 7) * BN;
        Ab = x16; Bb = w16 + (size_t)role * 1048576;
        Cb = role ? k16 : q16; bias = role ? bk : bq;
    } else {
        int f = idx - 1024;               // 0..63
        mBase = (f >> 3) * BM; nBase = (f & 7) * BN;
        Ab = w16 + (size_t)2 * 1048576;   // Wo
        Bb = w16 + (size_t)3 * 1048576;   // WvT
        Cb = F16; bias = nullptr;
    }

    const int tid  = threadIdx.x;
    const int lane = tid & 63;
    const int wave = tid >> 6;
    const int quad = lane >> 4;
    const int l16  = lane & 15;
    const int wr   = wave >> 1;
    const int wc   = wave & 1;

    f32x4 acc[4][4] = {};
    gemm_core(Ab, Bb, ldsA, ldsB, mBase, nBase, lane, wave, 1024, acc);

    #pragma unroll
    for (int mi = 0; mi < 4; ++mi)
        #pragma unroll
        for (int ni = 0; ni < 4; ++ni) {
            int col = nBase + wc * 64 + ni * 16 + l16;
            float b = bias ? bias[col] : 0.f;
            #pragma unroll
            for (int r = 0; r < 4; ++r) {
                int row = mBase + wr * 64 + mi * 16 + quad * 4 + r;
                Cb[(size_t)row * 1024 + col] = f32_to_bf16_rne(acc[mi][ni][r] + b);
            }
        }
}

// ---------------------------------------------------------------------------
// R9: phase-split wide-tile GEMM (m201-style schedule, plain HIP).
// 8 waves (2m x 4n), BK=64, per-wave tile RWx64, acc[MI][4].
// K-tile t computed in NPH phases (m-strips of 32 rows/wave, 16 MFMA each
// for 256-wide A; B frags live in registers across the tile).
// Staging (global_load_lds, 16B, pre-swizzled source, linear LDS dest):
//   phase 0: strip_{NPH-1}(t+1)  -> buf^1   (slot freed at (t-1).P_{NPH-1})
//   phase 1: B(t+2) + strip0(t+2)-> buf     (B/strip0 freed at t.P0)
//   phase q>=2: strip_{q-1}(t+2) -> buf     (freed at t.P_{q-1})
//   last phase: s_waitcnt vmcnt(NWT) — exactly the t+2 loads stay in flight,
//   everything through tile t+1 has landed. Never drains to 0 in steady
//   state; issue->wait distance >= 2-3 phases.
// Raw s_barrier (x2/phase) + sched_barrier(0) fences; setprio(1) on MFMAs.
// MODE 3: C bf16 = exp(acc*alpha), atomic fp32 rowsums.
// MODE 6: C fp32 = acc/rowsum + b0.
// ---------------------------------------------------------------------------
template <int MODE, int BMt, int BNt>
__global__ __launch_bounds__(512) void gemm8p(
    const unsigned short* __restrict__ A,
    const unsigned short* __restrict__ Bt,
    void* __restrict__ C,
    const float* __restrict__ b0, float* __restrict__ rowsum,
    float alpha, int M, int N, int K,
    long long aZ, long long bZ, long long cZ,
    int MBt, int NB)
{
    constexpr int RW  = BMt / 2;           // rows per wave
    constexpr int CW  = BNt / 4;           // cols per wave (= 64)
    constexpr int MI  = RW / 16;           // m-frags per wave (8 or 4)
    constexpr int NI  = CW / 16;           // n-frags per wave (= 4)
    constexpr int NPH = MI / 2;            // phases per K-tile (strip = 2 frags)
    constexpr int BL  = (BNt * 64 / 512) / 8;  // B loads/wave/K-tile (= 4)
    constexpr int NWT = BL + NPH - 1;      // steady-state counted vmcnt

    __shared__ __align__(16) unsigned short ldsA[2][BMt * 64];
    __shared__ __align__(16) unsigned short ldsB[2][BNt * 64];

    // 2D XCD supertiling: 8 XCDs as 2(m) x 4(n), [zb][nbi][mb fastest].
    const int l   = blockIdx.x;
    const int xcd = l & 7;
    const int t   = l >> 3;
    const int MBX = MBt >> 1;
    const int NBX = NB >> 2;               // >= 1 for all our launches
    const int mbl = t % MBX;
    const int r1  = t / MBX;
    const int nbi = r1 % NBX;
    const int zb  = r1 / NBX;
    const int mb  = (xcd >> 2) * MBX + mbl;
    const int nb  = (xcd & 3) * NBX + nbi;

    const unsigned short* Ab = A  + (size_t)zb * aZ;
    const unsigned short* Bb = Bt + (size_t)zb * bZ;

    const int tid  = threadIdx.x;
    const int lane = tid & 63;
    const int wave = tid >> 6;
    const int quad = lane >> 4;
    const int l16  = lane & 15;
    const int wr   = wave >> 2;            // 0..1
    const int wc   = wave & 3;             // 0..3
    const int mBase = mb * BMt;
    const int nBase = nb * BNt;
    const int NT    = K >> 6;

    // each wave stages one 8-row octet per A-strip and 4 octets of B
    const int aRow0 = ((wave & 4) ? RW : 0) + (wave & 3) * 8;

    auto stageA = [&](int p, int kt, int q) {
        const int rowbase = aRow0 + q * 32;
        const int row = rowbase + (lane >> 3);
        const int col = (((lane & 7) ^ row) & 7) << 3;   // pre-swizzled source
        __builtin_amdgcn_global_load_lds(
            (const __attribute__((address_space(1))) void*)(
                Ab + (size_t)(mBase + row) * K + (size_t)((kt << 6) + col)),
            (__attribute__((address_space(3))) void*)(&ldsA[p][rowbase * 64]),
            16, 0, 0);
    };
    auto stageB = [&](int p, int kt) {
        #pragma unroll
        for (int i = 0; i < BL; ++i) {
            const int g   = wave * BL + i;
            const int row = (g << 3) + (lane >> 3);
            const int col = (((lane & 7) ^ row) & 7) << 3;
            __builtin_amdgcn_global_load_lds(
                (const __attribute__((address_space(1))) void*)(
                    Bb + (size_t)(nBase + row) * K + (size_t)((kt << 6) + col)),
                (__attribute__((address_space(3))) void*)(&ldsB[p][g << 9]),
                16, 0, 0);
        }
    };

    bf16x8 bf[NI][2];
    bf16x8 af[2][2];
    auto ldB = [&](int p) {
        #pragma unroll
        for (int n2 = 0; n2 < NI; ++n2)
            #pragma unroll
            for (int kk = 0; kk < 2; ++kk) {
                const int r = wc * CW + n2 * 16 + l16;
                const int c = kk * 4 + quad;
                bf[n2][kk] = *(const bf16x8*)&ldsB[p][r * 64 + (((c ^ r) & 7) << 3)];
            }
    };
    auto ldA = [&](int p, int q) {
        #pragma unroll
        for (int m2 = 0; m2 < 2; ++m2)
            #pragma unroll
            for (int kk = 0; kk < 2; ++kk) {
                const int r = wr * RW + (q * 2 + m2) * 16 + l16;
                const int c = kk * 4 + quad;
                af[m2][kk] = *(const bf16x8*)&ldsA[p][r * 64 + (((c ^ r) & 7) << 3)];
            }
    };

    f32x4 acc[MI][NI] = {};

    // ---- prologue: tile0 fully + tile1 all but its last strip ----
    stageB(0, 0);
    #pragma unroll
    for (int q = 0; q < NPH; ++q) stageA(0, 0, q);
    if (NT > 1) {
        stageB(1, 1);
        #pragma unroll
        for (int q = 0; q < NPH - 1; ++q) stageA(1, 1, q);
        asm volatile("s_waitcnt vmcnt(%0)" :: "n"(NWT) : "memory");
    } else {
        asm volatile("s_waitcnt vmcnt(0)" ::: "memory");
    }
    __builtin_amdgcn_s_barrier();

    // ---- main loop ----
    for (int kt = 0; kt < NT; ++kt) {
        const int p = kt & 1;
        #pragma unroll
        for (int q = 0; q < NPH; ++q) {
            if (q == 0) ldB(p);
            ldA(p, q);
            if (q == 0) {
                if (kt + 1 < NT) stageA(p ^ 1, kt + 1, NPH - 1);
            } else if (q == 1) {
                if (kt + 2 < NT) { stageB(p, kt + 2); stageA(p, kt + 2, 0); }
            } else {
                if (kt + 2 < NT) stageA(p, kt + 2, q - 1);
            }
            if (q == NPH - 1) {
                if (kt + 2 < NT) {
                    asm volatile("s_waitcnt vmcnt(%0)" :: "n"(NWT) : "memory");
                } else if (kt + 1 < NT) {
                    asm volatile("s_waitcnt vmcnt(0)" ::: "memory");
                }
            }
            __builtin_amdgcn_sched_barrier(0);
            __builtin_amdgcn_s_barrier();
            __builtin_amdgcn_sched_barrier(0);
            __builtin_amdgcn_s_setprio(1);
            #pragma unroll
            for (int m2 = 0; m2 < 2; ++m2)
                #pragma unroll
                for (int n2 = 0; n2 < NI; ++n2)
                    #pragma unroll
                    for (int kk = 0; kk < 2; ++kk)
                        acc[q * 2 + m2][n2] = __builtin_amdgcn_mfma_f32_16x16x32_bf16(
                            af[m2][kk], bf[n2][kk], acc[q * 2 + m2][n2], 0, 0, 0);
            __builtin_amdgcn_s_setprio(0);
            __builtin_amdgcn_sched_barrier(0);
            __builtin_amdgcn_s_barrier();
            __builtin_amdgcn_sched_barrier(0);
        }
    }

    // ---- epilogues. C/D layout: col = l16, row = quad*4 + reg ----
    if constexpr (MODE == 3) {
        unsigned short* Pz = (unsigned short*)C + (size_t)zb * cZ;
        float* rs = rowsum + (size_t)zb * M;
        #pragma unroll
        for (int mi = 0; mi < MI; ++mi) {
            #pragma unroll
            for (int r = 0; r < 4; ++r) {
                const int row = mBase + wr * RW + mi * 16 + quad * 4 + r;
                float e[NI];
                float partial = 0.f;
                #pragma unroll
                for (int ni = 0; ni < NI; ++ni) {
                    e[ni] = __expf(acc[mi][ni][r] * alpha);
                    partial += e[ni];
                }
                #pragma unroll
                for (int ni = 0; ni < NI; ++ni) {
                    const int col = nBase + wc * CW + ni * 16 + l16;
                    Pz[(size_t)row * N + col] = f32_to_bf16_rne(e[ni]);
                }
                #pragma unroll
                for (int off = 1; off < 16; off <<= 1)
                    partial += __shfl_xor(partial, off, 64);
                if (l16 == 0) atomicAdd(&rs[row], partial);
            }
        }
    } else {  // MODE 6
        float* Cz = (float*)C + (size_t)zb * cZ;
        const float* rs = rowsum + (size_t)zb * M;
        #pragma unroll
        for (int mi = 0; mi < MI; ++mi) {
            #pragma unroll
            for (int r = 0; r < 4; ++r) {
                const int row = mBase + wr * RW + mi * 16 + quad * 4 + r;
                const float inv = 1.f / rs[row];
                #pragma unroll
                for (int ni = 0; ni < NI; ++ni) {
                    const int col = nBase + wc * CW + ni * 16 + l16;
                    Cz[(size_t)row * N + col] = acc[mi][ni][r] * inv + b0[col];
                }
            }
        }
    }
}

// ---------------------------------------------------------------------------
extern "C" void kernel_launch(void* const* d_in, const int* in_sizes, int n_in,
                              void* d_out, int out_size, void* d_ws, size_t ws_size,
                              hipStream_t stream)
{
    const float* x  = (const float*)d_in[0];
    const float* Wq = (const float*)d_in[1];
    const float* bq = (const float*)d_in[2];
    const float* Wk = (const float*)d_in[3];
    const float* bk = (const float*)d_in[4];
    const float* Wv = (const float*)d_in[5];
    const float* bv = (const float*)d_in[6];
    const float* Wo = (const float*)d_in[7];
    const float* bo = (const float*)d_in[8];
    float* out = (float*)d_out;

    const int S = 4096, H = 1024, Bsz = 2;
    const int M = Bsz * S;   // 8192

    char* p = (char*)d_ws;
    auto alloc = [&](size_t bytes) -> char* {
        char* r = p; p += (bytes + 255) & ~(size_t)255; return r;
    };
    unsigned short* w16  = (unsigned short*)alloc((size_t)4 * H * H * 2);  // Wq|Wk|Wo|WvT
    unsigned short* F16  = (unsigned short*)alloc((size_t)H * H * 2);
    unsigned short* q16  = (unsigned short*)alloc((size_t)M * H * 2);
    unsigned short* k16  = (unsigned short*)alloc((size_t)M * H * 2);
    unsigned short* vot16= (unsigned short*)alloc((size_t)Bsz * H * S * 2); // [B][H][S]
    float*          rsum = (float*)alloc((size_t)M * 4);
    float*          bfin = (float*)alloc((size_t)H * 4);
    // region (64 MB): x16 (16 MB head; read by QKF and Vot, both BEFORE the
    // scores dispatch that overwrites it via p16)
    char* region = alloc((size_t)Bsz * S * S * 2);
    unsigned short* x16 = (unsigned short*)region;
    unsigned short* p16 = (unsigned short*)region;

    // 1) converts + Wv transpose + bfinal + rowsum zeroing
    cvt_all<<<11544, 256, 0, stream>>>(x, Wq, Wk, Wo, Wv, bv, bo,
                                       x16, w16, rsum, bfin);

    // 2) q, k projections + F = Wo.Wv
    gemm_qkf<<<1088, 256, 0, stream>>>(x16, w16, q16, k16, F16, bq, bk);

    // 3) Vot[b] = F . x_b^T  -> bf16 [H][S]
    gemm_bt<1><<<dim3(S / BN, H / BM, 2), 256, 0, stream>>>(
        F16, x16, vot16, nullptr, nullptr, 1.f, H, S, 1024,
        0, (long long)S * H, (long long)H * S);

    // 4) P_un[b] = exp(q k^T / 8) + atomic rowsums   (256x256, phase-split)
    gemm8p<3, 256, 256><<<512, 512, 0, stream>>>(
        q16, k16, p16, nullptr, rsum, 0.125f, S, S, 1024,
        (long long)S * H, (long long)S * H, (long long)S * S, 16, 16);

    // 5) out[b] = (P_un . Vot^T)/rowsum + bfinal     (128x256, phase-split)
    gemm8p<6, 128, 256><<<256, 512, 0, stream>>>(
        p16, vot16, out, bfin, rsum, 1.f, S, H, 4096,
        (long long)S * S, (long long)H * S, (long long)S * H, 32, 4);
}

// Round 2
// 369.330 us; speedup vs baseline: 1.0063x; 1.0063x over previous
//
#include <hip/hip_runtime.h>
#include <stdint.h>

// ---------------------------------------------------------------------------
// DistributedAttention on MI355X (gfx950)
//   q = x Wq^T + bq ; k = x Wk^T + bk ; v = x Wv^T + bv
//   P = softmax(q k^T / 8) ; out = P v Wo^T + bo
// Factorization (R7, kept):
//   F    = Wo . Wv                  (2.1 GF, replaces the 17.2 GF v-proj)
//   Vot  = F . x^T   per batch      ([H][S] bf16)
//   P_un = exp(q k^T / 8)           (bf16 + atomic fp32 rowsums)
//   out  = (P_un . Vot^T)/rowsum + bfinal,  bfinal = bo + Wo.bv
// R10: post-mortem of R9 — phase-split (gemm8p) regressed scores (K=1024,
//   2 serial 1-blk/CU rounds, 8-wave lockstep; real MFMA util ~7%) but
//   improved final (K=4096, ~81 vs 95 µs). So:
//   (1) scores REVERTED to the proven 128^2 gemm_bt<3> (95 µs, 3 blk/CU).
//   (2) final keeps gemm8p<6,128,256>, made template-exact (m201): per
//       phase {ds_read + stage issue + [counted vmcnt] -> s_barrier ->
//       asm lgkmcnt(0) + sched_barrier(0) (rule #18) -> setprio(1) MFMA
//       setprio(0) -> s_barrier}. The 3 extra sched_barrier(0) fences per
//       phase are REMOVED (they pinned addr-math/stage-issue out of the
//       MFMA window). Race-free: the explicit lgkmcnt(0) pins each wave's
//       LDS reads complete before the end barrier; stage-writes to a slot
//       are issued only after the barrier following its last read.
// ---------------------------------------------------------------------------

typedef __bf16 bf16x8 __attribute__((ext_vector_type(8)));
typedef float  f32x4  __attribute__((ext_vector_type(4)));

__device__ __forceinline__ unsigned short f32_to_bf16_rne(float f) {
    uint32_t u = __builtin_bit_cast(uint32_t, f);
    uint32_t r = (u + 0x7FFFu + ((u >> 16) & 1u)) >> 16;
    return (unsigned short)r;
}

#define BM 128
#define BN 128
#define BK 64

// ---------------------------------------------------------------------------
// One-dispatch prep, 11544 blocks (unchanged).
// ---------------------------------------------------------------------------
__global__ __launch_bounds__(256) void cvt_all(
    const float* __restrict__ x,
    const float* __restrict__ Wq, const float* __restrict__ Wk,
    const float* __restrict__ Wo, const float* __restrict__ Wv,
    const float* __restrict__ bv, const float* __restrict__ bo,
    unsigned short* __restrict__ x16, unsigned short* __restrict__ w16,
    float* __restrict__ rsum, float* __restrict__ bfinal)
{
    const int b = blockIdx.x, tid = threadIdx.x;
    if (b < 8192) {
        int i = (b * 256 + tid) * 4;
        float4 v = *(const float4*)(x + i);
        ushort4 o;
        o.x = f32_to_bf16_rne(v.x); o.y = f32_to_bf16_rne(v.y);
        o.z = f32_to_bf16_rne(v.z); o.w = f32_to_bf16_rne(v.w);
        *(ushort4*)(x16 + i) = o;
    } else if (b < 11264) {
        int bb = b - 8192;
        int which = bb >> 10;
        const float* src = which == 0 ? Wq : which == 1 ? Wk : Wo;
        int i = ((bb & 1023) * 256 + tid) * 4;
        float4 v = *(const float4*)(src + i);
        ushort4 o;
        o.x = f32_to_bf16_rne(v.x); o.y = f32_to_bf16_rne(v.y);
        o.z = f32_to_bf16_rne(v.z); o.w = f32_to_bf16_rne(v.w);
        *(ushort4*)(w16 + (size_t)which * 1048576 + i) = o;
    } else if (b < 11520) {
        __shared__ unsigned short tl[64 * 68];   // [c][r], stride 68
        int t = b - 11264, tr = t >> 4, tc = t & 15;
        #pragma unroll
        for (int it = 0; it < 4; ++it) {
            int r  = it * 16 + (tid >> 4);
            int c0 = (tid & 15) * 4;
            float4 v = *(const float4*)(Wv + (size_t)(tr * 64 + r) * 1024 + tc * 64 + c0);
            tl[(c0 + 0) * 68 + r] = f32_to_bf16_rne(v.x);
            tl[(c0 + 1) * 68 + r] = f32_to_bf16_rne(v.y);
            tl[(c0 + 2) * 68 + r] = f32_to_bf16_rne(v.z);
            tl[(c0 + 3) * 68 + r] = f32_to_bf16_rne(v.w);
        }
        __syncthreads();
        #pragma unroll
        for (int it = 0; it < 4; ++it) {
            int c  = it * 16 + (tid >> 4);
            int r0 = (tid & 15) * 4;
            ushort4 o;
            o.x = tl[c * 68 + r0 + 0]; o.y = tl[c * 68 + r0 + 1];
            o.z = tl[c * 68 + r0 + 2]; o.w = tl[c * 68 + r0 + 3];
            *(ushort4*)(w16 + (size_t)3 * 1048576 + (size_t)(tc * 64 + c) * 1024 + tr * 64 + r0) = o;
        }
    } else if (b < 11536) {
        int bb = b - 11520;
        int lane = tid & 63, wv_ = tid >> 6;
        int rowBase = bb * 64 + wv_ * 16;
        for (int rr = 0; rr < 16; ++rr) {
            int row = rowBase + rr;
            float partial = 0.f;
            #pragma unroll
            for (int t2 = 0; t2 < 16; ++t2) {
                int h = t2 * 64 + lane;
                partial += Wo[(size_t)row * 1024 + h] * bv[h];
            }
            #pragma unroll
            for (int off = 32; off > 0; off >>= 1)
                partial += __shfl_xor(partial, off, 64);
            if (lane == 0) bfinal[row] = bo[row] + partial;
        }
    } else {
        int i = ((b - 11536) * 256 + tid) * 4;
        *(float4*)(rsum + i) = float4{0.f, 0.f, 0.f, 0.f};
    }
}

// ---------------------------------------------------------------------------
// Proven 128^2 K-loop (R5 codegen) — QKF, Vot, and scores.
// ---------------------------------------------------------------------------
__device__ __forceinline__ void gemm_core(
    const unsigned short* __restrict__ Ab,
    const unsigned short* __restrict__ Bb,
    unsigned short* ldsA, unsigned short* ldsB,
    int mBase, int nBase, int lane, int wave, int K, f32x4 (&acc)[4][4])
{
    const int quad = lane >> 4;
    const int l16  = lane & 15;
    const int wr   = wave >> 1;
    const int wc   = wave & 1;

    for (int k0 = 0; k0 < K; k0 += BK) {
        #pragma unroll
        for (int i = 0; i < 4; ++i) {
            int base = (i * 4 + wave) * 64;
            int s    = base + lane;
            int row  = s >> 3;
            int col  = ((s ^ (s >> 3)) & 7) * 8;
            __builtin_amdgcn_global_load_lds(
                (const __attribute__((address_space(1))) void*)(Ab + (size_t)(mBase + row) * K + (size_t)(k0 + col)),
                (__attribute__((address_space(3))) void*)(&ldsA[base * 8]),
                16, 0, 0);
        }
        #pragma unroll
        for (int i = 0; i < 4; ++i) {
            int base = (i * 4 + wave) * 64;
            int s    = base + lane;
            int row  = s >> 3;
            int col  = ((s ^ (s >> 3)) & 7) * 8;
            __builtin_amdgcn_global_load_lds(
                (const __attribute__((address_space(1))) void*)(Bb + (size_t)(nBase + row) * K + (size_t)(k0 + col)),
                (__attribute__((address_space(3))) void*)(&ldsB[base * 8]),
                16, 0, 0);
        }
        __syncthreads();

        #pragma unroll
        for (int kk = 0; kk < 2; ++kk) {
            bf16x8 af[4], bfv[4];
            #pragma unroll
            for (int mi = 0; mi < 4; ++mi) {
                int r = wr * 64 + mi * 16 + l16;
                int c = kk * 4 + quad;
                af[mi] = *(const bf16x8*)(&ldsA[r * BK + (((c ^ r) & 7) << 3)]);
            }
            #pragma unroll
            for (int ni = 0; ni < 4; ++ni) {
                int r = wc * 64 + ni * 16 + l16;
                int c = kk * 4 + quad;
                bfv[ni] = *(const bf16x8*)(&ldsB[r * BK + (((c ^ r) & 7) << 3)]);
            }
            #pragma unroll
            for (int mi = 0; mi < 4; ++mi)
                #pragma unroll
                for (int ni = 0; ni < 4; ++ni)
                    acc[mi][ni] = __builtin_amdgcn_mfma_f32_16x16x32_bf16(
                        af[mi], bfv[ni], acc[mi][ni], 0, 0, 0);
        }
        __syncthreads();
    }
}

// ---------------------------------------------------------------------------
// Generic z-batched A.Bt^T GEMM, 128^2 path.
// MODE 1: C bf16 (+optional bias). MODE 3: scores (exp + atomic rowsums).
// ---------------------------------------------------------------------------
template <int MODE>
__global__ __launch_bounds__(256) void gemm_bt(
    const unsigned short* __restrict__ A,
    const unsigned short* __restrict__ Bt,
    void* __restrict__ C,
    const float* __restrict__ b0, float* __restrict__ rowsum,
    float alpha, int M, int N, int K,
    long long aZ, long long bZ, long long cZ)
{
    __shared__ unsigned short ldsA[BM * BK];
    __shared__ unsigned short ldsB[BN * BK];

    const int NB = gridDim.x, MBt = gridDim.y;
    int l  = blockIdx.x + gridDim.x * (blockIdx.y + gridDim.y * blockIdx.z);
    int xcd = l & 7;
    int t   = l >> 3;
    int MBX = MBt >> 1;
    int NBX = NB >> 2;
    int mbl = t % MBX;
    int r1  = t / MBX;
    int nbi = r1 % NBX;
    int zb  = r1 / NBX;
    int mb  = (xcd >> 2) * MBX + mbl;
    int nb  = (xcd & 3) * NBX + nbi;

    const unsigned short* Ab = A  + (size_t)zb * aZ;
    const unsigned short* Bb = Bt + (size_t)zb * bZ;

    const int tid  = threadIdx.x;
    const int lane = tid & 63;
    const int wave = tid >> 6;
    const int quad = lane >> 4;
    const int l16  = lane & 15;
    const int wr   = wave >> 1;
    const int wc   = wave & 1;
    const int mBase = mb * BM;
    const int nBase = nb * BN;

    f32x4 acc[4][4] = {};
    gemm_core(Ab, Bb, ldsA, ldsB, mBase, nBase, lane, wave, K, acc);

    if (MODE == 1) {
        unsigned short* Cz = (unsigned short*)C + (size_t)zb * cZ;
        #pragma unroll
        for (int mi = 0; mi < 4; ++mi)
            #pragma unroll
            for (int ni = 0; ni < 4; ++ni) {
                int col = nBase + wc * 64 + ni * 16 + l16;
                float b = b0 ? b0[col] : 0.f;
                #pragma unroll
                for (int r = 0; r < 4; ++r) {
                    int row = mBase + wr * 64 + mi * 16 + quad * 4 + r;
                    Cz[(size_t)row * N + col] = f32_to_bf16_rne(acc[mi][ni][r] + b);
                }
            }
    } else if (MODE == 3) {
        unsigned short* Pz = (unsigned short*)C + (size_t)zb * cZ;
        float* rs = rowsum + (size_t)zb * M;
        #pragma unroll
        for (int mi = 0; mi < 4; ++mi) {
            #pragma unroll
            for (int r = 0; r < 4; ++r) {
                int row = mBase + wr * 64 + mi * 16 + quad * 4 + r;
                float e[4];
                float partial = 0.f;
                #pragma unroll
                for (int ni = 0; ni < 4; ++ni) {
                    e[ni] = __expf(acc[mi][ni][r] * alpha);
                    partial += e[ni];
                }
                #pragma unroll
                for (int ni = 0; ni < 4; ++ni) {
                    int col = nBase + wc * 64 + ni * 16 + l16;
                    Pz[(size_t)row * N + col] = f32_to_bf16_rne(e[ni]);
                }
                #pragma unroll
                for (int off = 1; off < 16; off <<= 1)
                    partial += __shfl_xor(partial, off, 64);
                if (l16 == 0) atomicAdd(&rs[row], partial);
            }
        }
    }
}

// ---------------------------------------------------------------------------
// Q/K projections + F = Wo.Wv in one dispatch (unchanged).
// ---------------------------------------------------------------------------
__global__ __launch_bounds__(256) void gemm_qkf(
    const unsigned short* __restrict__ x16,
    const unsigned short* __restrict__ w16,   // [Wq|Wk|Wo|WvT] x 1048576 elems
    unsigned short* __restrict__ q16,
    unsigned short* __restrict__ k16,
    unsigned short* __restrict__ F16,
    const float* __restrict__ bq, const float* __restrict__ bk)
{
    __shared__ unsigned short ldsA[BM * BK];
    __shared__ unsigned short ldsB[BN * BK];

    int l   = blockIdx.x;                 // 1088 = 8 * 136
    int idx = (l & 7) * 136 + (l >> 3);   // XCD-contiguous

    const unsigned short *Ab, *Bb;
    unsigned short* Cb;
    const float* bias;
    int mBase, nBase;
    if (idx < 1024) {
        int role = idx >> 9;              // 0:q 1:k
        int s    = idx & 511;
        mBase = (s >> 3) * BM; nBase = (s & 7) * BN;
        Ab = x16; Bb = w16 + (size_t)role * 1048576;
        Cb = role ? k16 : q16; bias = role ? bk : bq;
    } else {
        int f = idx - 1024;               // 0..63
        mBase = (f >> 3) * BM; nBase = (f & 7) * BN;
        Ab = w16 + (size_t)2 * 1048576;   // Wo
        Bb = w16 + (size_t)3 * 1048576;   // WvT
        Cb = F16; bias = nullptr;
    }

    const int tid  = threadIdx.x;
    const int lane = tid & 63;
    const int wave = tid >> 6;
    const int quad = lane >> 4;
    const int l16  = lane & 15;
    const int wr   = wave >> 1;
    const int wc   = wave & 1;

    f32x4 acc[4][4] = {};
    gemm_core(Ab, Bb, ldsA, ldsB, mBase, nBase, lane, wave, 1024, acc);

    #pragma unroll
    for (int mi = 0; mi < 4; ++mi)
        #pragma unroll
        for (int ni = 0; ni < 4; ++ni) {
            int col = nBase + wc * 64 + ni * 16 + l16;
            float b = bias ? bias[col] : 0.f;
            #pragma unroll
            for (int r = 0; r < 4; ++r) {
                int row = mBase + wr * 64 + mi * 16 + quad * 4 + r;
                Cb[(size_t)row * 1024 + col] = f32_to_bf16_rne(acc[mi][ni][r] + b);
            }
        }
}

// ---------------------------------------------------------------------------
// R10: phase-split GEMM for the final op only (K=4096 amortizes the
// pipeline). 8 waves (2m x 4n), BK=64, double-buffered xor-swizzled LDS,
// global_load_lds(16B), counted vmcnt once per K-tile (never 0 in steady
// state). Phase = {ds_read subtile + stage issue -> s_barrier ->
// asm lgkmcnt(0) + sched_barrier(0) -> setprio(1) 16xMFMA setprio(0) ->
// s_barrier}  (m201 template-exact; no blanket sched_barrier fences).
// MODE 6: C fp32 = acc/rowsum + b0.
// ---------------------------------------------------------------------------
template <int MODE, int BMt, int BNt>
__global__ __launch_bounds__(512) void gemm8p(
    const unsigned short* __restrict__ A,
    const unsigned short* __restrict__ Bt,
    void* __restrict__ C,
    const float* __restrict__ b0, float* __restrict__ rowsum,
    float alpha, int M, int N, int K,
    long long aZ, long long bZ, long long cZ,
    int MBt, int NB)
{
    constexpr int RW  = BMt / 2;           // rows per wave
    constexpr int CW  = BNt / 4;           // cols per wave (= 64)
    constexpr int MI  = RW / 16;           // m-frags per wave
    constexpr int NI  = CW / 16;           // n-frags per wave (= 4)
    constexpr int NPH = MI / 2;            // phases per K-tile
    constexpr int BL  = (BNt * 64 / 512) / 8;  // B loads/wave/K-tile (= 4)
    constexpr int NWT = BL + NPH - 1;      // steady-state counted vmcnt

    __shared__ __align__(16) unsigned short ldsA[2][BMt * 64];
    __shared__ __align__(16) unsigned short ldsB[2][BNt * 64];

    // 2D XCD supertiling: 8 XCDs as 2(m) x 4(n), [zb][nbi][mb fastest].
    const int l   = blockIdx.x;
    const int xcd = l & 7;
    const int t   = l >> 3;
    const int MBX = MBt >> 1;
    const int NBX = NB >> 2;
    const int mbl = t % MBX;
    const int r1  = t / MBX;
    const int nbi = r1 % NBX;
    const int zb  = r1 / NBX;
    const int mb  = (xcd >> 2) * MBX + mbl;
    const int nb  = (xcd & 3) * NBX + nbi;

    const unsigned short* Ab = A  + (size_t)zb * aZ;
    const unsigned short* Bb = Bt + (size_t)zb * bZ;

    const int tid  = threadIdx.x;
    const int lane = tid & 63;
    const int wave = tid >> 6;
    const int quad = lane >> 4;
    const int l16  = lane & 15;
    const int wr   = wave >> 2;            // 0..1
    const int wc   = wave & 3;             // 0..3
    const int mBase = mb * BMt;
    const int nBase = nb * BNt;
    const int NT    = K >> 6;

    // each wave stages one 8-row octet per A-strip and 4 octets of B
    const int aRow0 = ((wave & 4) ? RW : 0) + (wave & 3) * 8;

    auto stageA = [&](int p, int kt, int q) {
        const int rowbase = aRow0 + q * 32;
        const int row = rowbase + (lane >> 3);
        const int col = (((lane & 7) ^ row) & 7) << 3;   // pre-swizzled source
        __builtin_amdgcn_global_load_lds(
            (const __attribute__((address_space(1))) void*)(
                Ab + (size_t)(mBase + row) * K + (size_t)((kt << 6) + col)),
            (__attribute__((address_space(3))) void*)(&ldsA[p][rowbase * 64]),
            16, 0, 0);
    };
    auto stageB = [&](int p, int kt) {
        #pragma unroll
        for (int i = 0; i < BL; ++i) {
            const int g   = wave * BL + i;
            const int row = (g << 3) + (lane >> 3);
            const int col = (((lane & 7) ^ row) & 7) << 3;
            __builtin_amdgcn_global_load_lds(
                (const __attribute__((address_space(1))) void*)(
                    Bb + (size_t)(nBase + row) * K + (size_t)((kt << 6) + col)),
                (__attribute__((address_space(3))) void*)(&ldsB[p][g << 9]),
                16, 0, 0);
        }
    };

    bf16x8 bf[NI][2];
    bf16x8 af[2][2];
    auto ldB = [&](int p) {
        #pragma unroll
        for (int n2 = 0; n2 < NI; ++n2)
            #pragma unroll
            for (int kk = 0; kk < 2; ++kk) {
                const int r = wc * CW + n2 * 16 + l16;
                const int c = kk * 4 + quad;
                bf[n2][kk] = *(const bf16x8*)&ldsB[p][r * 64 + (((c ^ r) & 7) << 3)];
            }
    };
    auto ldA = [&](int p, int q) {
        #pragma unroll
        for (int m2 = 0; m2 < 2; ++m2)
            #pragma unroll
            for (int kk = 0; kk < 2; ++kk) {
                const int r = wr * RW + (q * 2 + m2) * 16 + l16;
                const int c = kk * 4 + quad;
                af[m2][kk] = *(const bf16x8*)&ldsA[p][r * 64 + (((c ^ r) & 7) << 3)];
            }
    };

    f32x4 acc[MI][NI] = {};

    // ---- prologue: tile0 fully + tile1 all but its last strip ----
    stageB(0, 0);
    #pragma unroll
    for (int q = 0; q < NPH; ++q) stageA(0, 0, q);
    if (NT > 1) {
        stageB(1, 1);
        #pragma unroll
        for (int q = 0; q < NPH - 1; ++q) stageA(1, 1, q);
        asm volatile("s_waitcnt vmcnt(%0)" :: "n"(NWT) : "memory");
    } else {
        asm volatile("s_waitcnt vmcnt(0)" ::: "memory");
    }
    __builtin_amdgcn_s_barrier();

    // ---- main loop ----
    for (int kt = 0; kt < NT; ++kt) {
        const int p = kt & 1;
        #pragma unroll
        for (int q = 0; q < NPH; ++q) {
            if (q == 0) ldB(p);
            ldA(p, q);
            if (q == 0) {
                if (kt + 1 < NT) stageA(p ^ 1, kt + 1, NPH - 1);
            } else if (q == 1) {
                if (kt + 2 < NT) { stageB(p, kt + 2); stageA(p, kt + 2, 0); }
            } else {
                if (kt + 2 < NT) stageA(p, kt + 2, q - 1);
            }
            if (q == NPH - 1) {
                if (kt + 2 < NT) {
                    asm volatile("s_waitcnt vmcnt(%0)" :: "n"(NWT) : "memory");
                } else if (kt + 1 < NT) {
                    asm volatile("s_waitcnt vmcnt(0)" ::: "memory");
                }
            }
            __builtin_amdgcn_s_barrier();
            // pin all of this wave's ds_reads complete before the end
            // barrier (race-freedom of the slot-reuse protocol), and keep
            // MFMAs from hoisting above it (rule #18).
            asm volatile("s_waitcnt lgkmcnt(0)" ::: "memory");
            __builtin_amdgcn_sched_barrier(0);
            __builtin_amdgcn_s_setprio(1);
            #pragma unroll
            for (int m2 = 0; m2 < 2; ++m2)
                #pragma unroll
                for (int n2 = 0; n2 < NI; ++n2)
                    #pragma unroll
                    for (int kk = 0; kk < 2; ++kk)
                        acc[q * 2 + m2][n2] = __builtin_amdgcn_mfma_f32_16x16x32_bf16(
                            af[m2][kk], bf[n2][kk], acc[q * 2 + m2][n2], 0, 0, 0);
            __builtin_amdgcn_s_setprio(0);
            __builtin_amdgcn_s_barrier();
        }
    }

    // ---- epilogue. C/D layout: col = l16, row = quad*4 + reg ----
    {
        float* Cz = (float*)C + (size_t)zb * cZ;
        const float* rs = rowsum + (size_t)zb * M;
        #pragma unroll
        for (int mi = 0; mi < MI; ++mi) {
            #pragma unroll
            for (int r = 0; r < 4; ++r) {
                const int row = mBase + wr * RW + mi * 16 + quad * 4 + r;
                const float inv = 1.f / rs[row];
                #pragma unroll
                for (int ni = 0; ni < NI; ++ni) {
                    const int col = nBase + wc * CW + ni * 16 + l16;
                    Cz[(size_t)row * N + col] = acc[mi][ni][r] * inv + b0[col];
                }
            }
        }
    }
}

// ---------------------------------------------------------------------------
extern "C" void kernel_launch(void* const* d_in, const int* in_sizes, int n_in,
                              void* d_out, int out_size, void* d_ws, size_t ws_size,
                              hipStream_t stream)
{
    const float* x  = (const float*)d_in[0];
    const float* Wq = (const float*)d_in[1];
    const float* bq = (const float*)d_in[2];
    const float* Wk = (const float*)d_in[3];
    const float* bk = (const float*)d_in[4];
    const float* Wv = (const float*)d_in[5];
    const float* bv = (const float*)d_in[6];
    const float* Wo = (const float*)d_in[7];
    const float* bo = (const float*)d_in[8];
    float* out = (float*)d_out;

    const int S = 4096, H = 1024, Bsz = 2;
    const int M = Bsz * S;   // 8192

    char* p = (char*)d_ws;
    auto alloc = [&](size_t bytes) -> char* {
        char* r = p; p += (bytes + 255) & ~(size_t)255; return r;
    };
    unsigned short* w16  = (unsigned short*)alloc((size_t)4 * H * H * 2);  // Wq|Wk|Wo|WvT
    unsigned short* F16  = (unsigned short*)alloc((size_t)H * H * 2);
    unsigned short* q16  = (unsigned short*)alloc((size_t)M * H * 2);
    unsigned short* k16  = (unsigned short*)alloc((size_t)M * H * 2);
    unsigned short* vot16= (unsigned short*)alloc((size_t)Bsz * H * S * 2); // [B][H][S]
    float*          rsum = (float*)alloc((size_t)M * 4);
    float*          bfin = (float*)alloc((size_t)H * 4);
    // region (64 MB): x16 (16 MB head; read by QKF and Vot, both BEFORE the
    // scores dispatch that overwrites it via p16)
    char* region = alloc((size_t)Bsz * S * S * 2);
    unsigned short* x16 = (unsigned short*)region;
    unsigned short* p16 = (unsigned short*)region;

    // 1) converts + Wv transpose + bfinal + rowsum zeroing
    cvt_all<<<11544, 256, 0, stream>>>(x, Wq, Wk, Wo, Wv, bv, bo,
                                       x16, w16, rsum, bfin);

    // 2) q, k projections + F = Wo.Wv
    gemm_qkf<<<1088, 256, 0, stream>>>(x16, w16, q16, k16, F16, bq, bk);

    // 3) Vot[b] = F . x_b^T  -> bf16 [H][S]
    gemm_bt<1><<<dim3(S / BN, H / BM, 2), 256, 0, stream>>>(
        F16, x16, vot16, nullptr, nullptr, 1.f, H, S, 1024,
        0, (long long)S * H, (long long)H * S);

    // 4) P_un[b] = exp(q k^T / 8) + atomic rowsums   (proven 128^2 path)
    gemm_bt<3><<<dim3(S / BN, S / BM, 2), 256, 0, stream>>>(
        q16, k16, p16, nullptr, rsum, 0.125f, S, S, 1024,
        (long long)S * H, (long long)S * H, (long long)S * S);

    // 5) out[b] = (P_un . Vot^T)/rowsum + bfinal     (128x256 phase-split)
    gemm8p<6, 128, 256><<<256, 512, 0, stream>>>(
        p16, vot16, out, bfin, rsum, 1.f, S, H, 4096,
        (long long)S * S, (long long)H * S, (long long)S * H, 32, 4);
}